// Round 1
// baseline (114.578 us; speedup 1.0000x reference)
//
#include <hip/hip_runtime.h>
#include <math.h>

// Problem constants (from reference)
#define BB 4
#define TT 1024
#define DD 1024
#define VV 32000
#define WW 8

// One block per (b, t) row.
//  - zero the 32000-float output row with float4 stores
//  - compute gate = sigmoid(dot(hidden[row], gate_w) + gate_b) via block reduce
//  - thread 0: softmax(lag_logits), dedup-accumulate <=8 lagged-token
//    contributions, plain stores into the (already zeroed) row.
__global__ __launch_bounds__(256) void recent_copy_bias_kernel(
    const float* __restrict__ hidden,      // (B,T,D) f32
    const int*   __restrict__ input_ids,   // (B,T)   int32 (harness-converted)
    const float* __restrict__ gate_w,      // (D,1)   f32
    const float* __restrict__ gate_b,      // (1,)    f32
    const float* __restrict__ lag_logits,  // (W,)    f32
    const float* __restrict__ copy_scale,  // (1,)    f32
    float*       __restrict__ out)         // (B,T,V) f32
{
    const int row = blockIdx.x;            // 0 .. B*T-1
    const int b   = row / TT;
    const int p   = row % TT;
    const int tid = threadIdx.x;

    // ---- 1. dot(hidden[row,:], gate_w[:,0]) : each thread one float4 ----
    const float4* h4 = reinterpret_cast<const float4*>(hidden + (size_t)row * DD);
    const float4* w4 = reinterpret_cast<const float4*>(gate_w);
    float4 hv = h4[tid];       // DD/4 == 256 == blockDim.x
    float4 wv = w4[tid];
    float s = hv.x * wv.x + hv.y * wv.y + hv.z * wv.z + hv.w * wv.w;

    // wave(64) butterfly reduce
    #pragma unroll
    for (int off = 32; off > 0; off >>= 1)
        s += __shfl_down(s, off, 64);

    __shared__ float partial[4];
    const int wave = tid >> 6;
    const int lane = tid & 63;
    if (lane == 0) partial[wave] = s;

    // ---- 2. zero this output row (coalesced float4 stores) ----
    float4* orow4 = reinterpret_cast<float4*>(out + (size_t)row * VV);
    const float4 z4 = make_float4(0.f, 0.f, 0.f, 0.f);
    // VV/4 = 8000 float4s per row
    #pragma unroll 4
    for (int i = tid; i < VV / 4; i += 256)
        orow4[i] = z4;

    __syncthreads();   // row fully zeroed + partials visible

    // ---- 3. scatter (single thread; <=8 entries, dedup deterministic) ----
    if (tid == 0) {
        float dot = partial[0] + partial[1] + partial[2] + partial[3];
        float gate = 1.0f / (1.0f + __expf(-(dot + gate_b[0])));

        // softmax over 8 lag logits
        float lw[WW];
        float m = -1e30f;
        #pragma unroll
        for (int i = 0; i < WW; ++i) { lw[i] = lag_logits[i]; m = fmaxf(m, lw[i]); }
        float sum = 0.f;
        #pragma unroll
        for (int i = 0; i < WW; ++i) { lw[i] = __expf(lw[i] - m); sum += lw[i]; }
        const float scale = copy_scale[0] * gate / sum;

        const int nl = (p + 1 < WW) ? (p + 1) : WW;   // valid lags: p >= lag
        int   toks[WW];
        float contrib[WW];
        for (int l = 0; l < nl; ++l) {
            toks[l]    = input_ids[b * TT + p - l];
            contrib[l] = scale * lw[l];
        }

        float* orow = out + (size_t)row * VV;
        for (int i = 0; i < nl; ++i) {
            bool first = true;
            for (int j = 0; j < i; ++j)
                if (toks[j] == toks[i]) { first = false; break; }
            if (!first) continue;
            float tot = contrib[i];
            for (int j = i + 1; j < nl; ++j)
                if (toks[j] == toks[i]) tot += contrib[j];
            orow[toks[i]] = tot;
        }
    }
}

extern "C" void kernel_launch(void* const* d_in, const int* in_sizes, int n_in,
                              void* d_out, int out_size, void* d_ws, size_t ws_size,
                              hipStream_t stream) {
    (void)in_sizes; (void)n_in; (void)d_ws; (void)ws_size;

    const float* hidden     = (const float*)d_in[0];
    const int*   input_ids  = (const int*)  d_in[1];
    const float* gate_w     = (const float*)d_in[2];
    const float* gate_b     = (const float*)d_in[3];
    const float* lag_logits = (const float*)d_in[4];
    const float* copy_scale = (const float*)d_in[5];
    float* out = (float*)d_out;

    dim3 grid(BB * TT);   // 4096 blocks, one per (b,t) row
    dim3 block(256);
    recent_copy_bias_kernel<<<grid, block, 0, stream>>>(
        hidden, input_ids, gate_w, gate_b, lag_logits, copy_scale, out);
}